// Round 3
// baseline (1622.218 us; speedup 1.0000x reference)
//
#include <hip/hip_runtime.h>
#include <hip/hip_bf16.h>
#include <stdint.h>

// B=8192, D_IN=1024, D_HID=4096, D_OUT=1024, E=8
#define BB 8192
#define DIN 1024
#define DHID 4096
#define DOUT 1024
#define NEXP 8
#define GH_N 2048  // D_HID/2

typedef __attribute__((ext_vector_type(8))) __bf16 bf16x8;
typedef __attribute__((ext_vector_type(4))) float f32x4;

__device__ inline unsigned short f2bf(float f) {
  unsigned u = __builtin_bit_cast(unsigned, f);
  u = (u + 0x7FFFu + ((u >> 16) & 1u)) >> 16;
  return (unsigned short)u;
}
__device__ inline float b2f(unsigned short s) {
  return __builtin_bit_cast(float, (unsigned)s << 16);
}

// ---------------- elementwise f32 -> bf16 ----------------
__global__ void cvt_f32_bf16(const float* __restrict__ in,
                             unsigned short* __restrict__ out, int n4) {
  int i = blockIdx.x * blockDim.x + threadIdx.x;
  if (i >= n4) return;
  float4 v = ((const float4*)in)[i];
  ushort4 o;
  o.x = f2bf(v.x); o.y = f2bf(v.y); o.z = f2bf(v.z); o.w = f2bf(v.w);
  ((ushort4*)out)[i] = o;
}

// ---------------- transpose + convert: in[R][C] f32 -> out[C][R] bf16 ----------------
__global__ void transpose_cvt(const float* __restrict__ in,
                              unsigned short* __restrict__ out, int R, int C) {
  __shared__ float tile[32][33];
  int c0 = blockIdx.x * 32, r0 = blockIdx.y * 32;
  int tx = threadIdx.x & 31, ty = threadIdx.x >> 5;  // ty in 0..7
#pragma unroll
  for (int i = 0; i < 4; ++i)
    tile[ty + i * 8][tx] = in[(size_t)(r0 + ty + i * 8) * C + c0 + tx];
  __syncthreads();
#pragma unroll
  for (int i = 0; i < 4; ++i)
    out[(size_t)(c0 + ty + i * 8) * R + r0 + tx] = f2bf(tile[tx][ty + i * 8]);
}

// ---------------- async global->LDS 16B ----------------
__device__ inline void gload16(const void* g, void* l) {
  __builtin_amdgcn_global_load_lds(
      (const __attribute__((address_space(1))) void*)g,
      (__attribute__((address_space(3))) void*)l, 16, 0, 0);
}

template <int N>
__device__ inline void waitv() {
  if constexpr (N == 0) asm volatile("s_waitcnt vmcnt(0)" ::: "memory");
  else if constexpr (N == 2) asm volatile("s_waitcnt vmcnt(2)" ::: "memory");
  else asm volatile("s_waitcnt vmcnt(0)" ::: "memory");
}
__device__ inline void waitlgkm0() {
  asm volatile("s_waitcnt lgkmcnt(0)" ::: "memory");
  __builtin_amdgcn_sched_barrier(0);
}

// ---------------- occupancy-first GEMM: C[M,N] = A[M,K]*Bt[N,K]^T ----------------
// 128x128 tile, 8 waves (4M x 2N), BK=32, 3-buffer LDS ring (48KB -> 2 blocks/CU),
// stage 2 tiles ahead, counted vmcnt(2), one barrier per K-tile.
// EPI 0: outb = bf16(relu(acc + bias[col]))
// EPI 1: outf = (accum? outf : 0) + gates[row*8+eidx]*(acc + bias[col])
template <int EPI>
__global__ __launch_bounds__(512, 4)
void gemmO(const unsigned short* __restrict__ A,
           const unsigned short* __restrict__ Bt,
           int M, int N, int K,
           const float* __restrict__ bias,
           unsigned short* __restrict__ outb,
           float* __restrict__ outf,
           const float* __restrict__ gates,
           int eidx, int accum) {
  constexpr int BK = 32;
  constexpr int TSZ = 128 * BK;  // shorts per buffer (8KB)
  __shared__ unsigned short As[3 * TSZ];
  __shared__ unsigned short Bs[3 * TSZ];

  const int t = threadIdx.x;
  const int lane = t & 63;
  const int wid = t >> 6;   // 0..7
  const int wm = wid >> 1;  // 0..3 -> rows wm*32
  const int wn = wid & 1;   // 0..1 -> cols wn*64

  // bijective XCD swizzle (all grids are multiples of 8); bm-major tile order
  // keeps same-bm (shared A-panel) tiles on one XCD.
  const int nwg = gridDim.x;
  const int flat = blockIdx.x;
  const int swz = (flat & 7) * (nwg >> 3) + (flat >> 3);
  const int nbn = N >> 7;
  const int bn = swz % nbn, bm = swz / nbn;
  const int m0 = bm << 7, n0 = bn << 7;

  // staging: thread t handles 16B chunk q=t of each 128x32 tile (512 chunks).
  // physical chunk cp at (row, logical chunk c = cp ^ ((row>>1)&3)) -- XOR swizzle.
  const int row = t >> 2, cp = t & 3;
  const int c = cp ^ ((row >> 1) & 3);
  const unsigned short* aS = A + (size_t)(m0 + row) * K + c * 8;
  const unsigned short* bS = Bt + (size_t)(n0 + row) * K + c * 8;
  const int qoff = t * 8;

  auto stage = [&](int T) {
    const int b = T % 3;
    const int k0 = T * BK;
    gload16(aS + k0, As + b * TSZ + qoff);
    gload16(bS + k0, Bs + b * TSZ + qoff);
  };

  // LDS read offsets (same XOR involution)
  const int l15 = lane & 15, lg = lane >> 4;
  int aoff[2], boff[4];
#pragma unroll
  for (int mi = 0; mi < 2; ++mi) {
    int r = wm * 32 + mi * 16 + l15;
    aoff[mi] = r * BK + ((lg ^ ((r >> 1) & 3)) << 3);
  }
#pragma unroll
  for (int ni = 0; ni < 4; ++ni) {
    int r = wn * 64 + ni * 16 + l15;
    boff[ni] = r * BK + ((lg ^ ((r >> 1) & 3)) << 3);
  }

  f32x4 acc[2][4];
  const f32x4 zero = {0.f, 0.f, 0.f, 0.f};
#pragma unroll
  for (int mi = 0; mi < 2; ++mi)
#pragma unroll
    for (int ni = 0; ni < 4; ++ni) acc[mi][ni] = zero;

  const int NT = K >> 5;

  // prologue: stage tiles 0,1; wait tile 0 landed (own loads), collective barrier.
  stage(0);
  stage(1);
  waitv<2>();
  __builtin_amdgcn_s_barrier();

  for (int T = 0; T < NT; ++T) {
    const int b = T % 3;
    const unsigned short* Ab = As + b * TSZ;
    const unsigned short* Bb = Bs + b * TSZ;
    bf16x8 af[2], bfr[4];
#pragma unroll
    for (int mi = 0; mi < 2; ++mi) af[mi] = *(const bf16x8*)(Ab + aoff[mi]);
#pragma unroll
    for (int ni = 0; ni < 4; ++ni) bfr[ni] = *(const bf16x8*)(Bb + boff[ni]);
    if (T + 2 < NT) stage(T + 2);  // overwrites buf (T-1)%3: all reads of it done
                                   // before the barrier at end of tile T-1.
    waitlgkm0();
    __builtin_amdgcn_s_setprio(1);
#pragma unroll
    for (int mi = 0; mi < 2; ++mi)
#pragma unroll
      for (int ni = 0; ni < 4; ++ni)
        acc[mi][ni] = __builtin_amdgcn_mfma_f32_16x16x32_bf16(
            af[mi], bfr[ni], acc[mi][ni], 0, 0, 0);
    __builtin_amdgcn_s_setprio(0);
    __builtin_amdgcn_sched_barrier(0);
    // retire next tile's stages (own loads) before the collective barrier:
    // after the barrier, buf (T+1)%3 is fully written by ALL waves.
    if (T + 2 < NT) waitv<2>();
    else if (T + 1 < NT) waitv<0>();
    __builtin_amdgcn_s_barrier();
  }

  // ---- epilogue: D row = lg*4 + reg, col = l15 (m89-verified) ----
  const int rb = m0 + wm * 32 + (lg << 2);
  const int cb = n0 + wn * 64 + l15;
  if (EPI == 0) {
#pragma unroll
    for (int mi = 0; mi < 2; ++mi) {
#pragma unroll
      for (int ni = 0; ni < 4; ++ni) {
        int col = cb + ni * 16;
        float bv = bias[col];
#pragma unroll
        for (int r = 0; r < 4; ++r) {
          int rowo = rb + mi * 16 + r;
          float v = acc[mi][ni][r] + bv;
          outb[(size_t)rowo * N + col] = f2bf(fmaxf(v, 0.f));
        }
      }
    }
  } else {
#pragma unroll
    for (int mi = 0; mi < 2; ++mi) {
      float g[4];
#pragma unroll
      for (int r = 0; r < 4; ++r)
        g[r] = gates[(size_t)(rb + mi * 16 + r) * NEXP + eidx];
#pragma unroll
      for (int ni = 0; ni < 4; ++ni) {
        int col = cb + ni * 16;
        float bv = bias[col];
#pragma unroll
        for (int r = 0; r < 4; ++r) {
          size_t o = (size_t)(rb + mi * 16 + r) * N + col;
          float v = (acc[mi][ni][r] + bv) * g[r];
          outf[o] = accum ? outf[o] + v : v;
        }
      }
    }
  }
}

// ---------------- gating head: logits = gh(bf16) @ gW2 + gb2, softmax over 8 ----------------
__global__ void gating_head(const unsigned short* __restrict__ gh,
                            const float* __restrict__ gW2,
                            const float* __restrict__ gb2,
                            float* __restrict__ gws,
                            float* __restrict__ g1,
                            float* __restrict__ g2, int B, int Kh) {
  int gw = (blockIdx.x * blockDim.x + threadIdx.x) >> 6;
  int lane = threadIdx.x & 63;
  int nw = (gridDim.x * blockDim.x) >> 6;
  for (int row = gw; row < B; row += nw) {
    float s[8] = {0, 0, 0, 0, 0, 0, 0, 0};
    for (int k = lane; k < Kh; k += 64) {
      float hv = b2f(gh[(size_t)row * Kh + k]);
      const float* w = gW2 + (size_t)k * 8;
#pragma unroll
      for (int e = 0; e < 8; ++e) s[e] += hv * w[e];
    }
#pragma unroll
    for (int e = 0; e < 8; ++e) {
#pragma unroll
      for (int off = 32; off > 0; off >>= 1) s[e] += __shfl_xor(s[e], off, 64);
    }
    if (lane == 0) {
      float l[8], m = -1e30f;
#pragma unroll
      for (int e = 0; e < 8; ++e) {
        l[e] = s[e] + gb2[e];
        m = fmaxf(m, l[e]);
      }
      float sum = 0.f;
#pragma unroll
      for (int e = 0; e < 8; ++e) {
        l[e] = expf(l[e] - m);
        sum += l[e];
      }
      float inv = 1.f / sum;
#pragma unroll
      for (int e = 0; e < 8; ++e) {
        float gv = l[e] * inv;
        gws[(size_t)row * 8 + e] = gv;
        g1[(size_t)row * 8 + e] = gv;
        g2[(size_t)row * 8 + e] = gv;
      }
    }
  }
}

extern "C" void kernel_launch(void* const* d_in, const int* in_sizes, int n_in,
                              void* d_out, int out_size, void* d_ws,
                              size_t ws_size, hipStream_t stream) {
  (void)in_sizes; (void)n_in; (void)out_size; (void)ws_size;
  const float* x   = (const float*)d_in[0];
  const float* gW1 = (const float*)d_in[1];
  const float* gb1 = (const float*)d_in[2];
  const float* gW2 = (const float*)d_in[3];
  const float* gb2 = (const float*)d_in[4];
  const float* eW1 = (const float*)d_in[5];
  const float* eb1 = (const float*)d_in[6];
  const float* eW2 = (const float*)d_in[7];
  const float* eb2 = (const float*)d_in[8];

  float* outC  = (float*)d_out;                       // [8192,1024]
  float* outG1 = outC + (size_t)BB * DOUT;            // [8192,8]
  float* outG2 = outG1 + (size_t)BB * NEXP;           // [8192,8]

  char* ws = (char*)d_ws;
  unsigned short* xb   = (unsigned short*)(ws);                 // 16,777,216 B
  unsigned short* gW1T = (unsigned short*)(ws + 16777216);      //  4,194,304 B
  unsigned short* gh   = (unsigned short*)(ws + 20971520);      // 33,554,432 B
  float*          gat  = (float*)(ws + 54525952);               //    262,144 B
  unsigned short* w1T  = (unsigned short*)(ws + 54788096);      //  8,388,608 B
  unsigned short* w2T  = (unsigned short*)(ws + 63176704);      //  8,388,608 B
  unsigned short* hbuf = (unsigned short*)(ws + 71565312);      // 67,108,864 B

  // x -> bf16
  cvt_f32_bf16<<<(BB * DIN / 4) / 256, 256, 0, stream>>>(x, xb, BB * DIN / 4);
  // gW1 [1024][2048] -> gW1T [2048][1024] bf16
  transpose_cvt<<<dim3(GH_N / 32, DIN / 32), 256, 0, stream>>>(gW1, gW1T, DIN, GH_N);
  // gh = relu(x @ gW1 + gb1)  [8192, 2048] bf16   grid 64*16=1024
  gemmO<0><<<dim3((BB / 128) * (GH_N / 128)), 512, 0, stream>>>(
      xb, gW1T, BB, GH_N, DIN, gb1, gh, nullptr, nullptr, 0, 0);
  // gates = softmax(gh @ gW2 + gb2)
  gating_head<<<256, 256, 0, stream>>>(gh, gW2, gb2, gat, outG1, outG2, BB, GH_N);

  for (int e = 0; e < NEXP; ++e) {
    // eW1_e [1024][4096] -> w1T [4096][1024]
    transpose_cvt<<<dim3(DHID / 32, DIN / 32), 256, 0, stream>>>(
        eW1 + (size_t)e * DIN * DHID, w1T, DIN, DHID);
    // eW2_e [4096][1024] -> w2T [1024][4096]
    transpose_cvt<<<dim3(DOUT / 32, DHID / 32), 256, 0, stream>>>(
        eW2 + (size_t)e * DHID * DOUT, w2T, DHID, DOUT);
    // h = relu(x @ eW1_e + eb1_e)  [8192, 4096] bf16   grid 64*32=2048
    gemmO<0><<<dim3((BB / 128) * (DHID / 128)), 512, 0, stream>>>(
        xb, w1T, BB, DHID, DIN, eb1 + (size_t)e * DHID, hbuf, nullptr, nullptr, 0, 0);
    // combined (+)= gates[:,e] * (h @ eW2_e + eb2_e)   grid 64*8=512 (2 blocks/CU)
    gemmO<1><<<dim3((BB / 128) * (DOUT / 128)), 512, 0, stream>>>(
        hbuf, w2T, BB, DOUT, DHID, eb2 + (size_t)e * DOUT, nullptr, outC, gat, e, e > 0);
  }
}

// Round 4
// 1416.173 us; speedup vs baseline: 1.1455x; 1.1455x over previous
//
#include <hip/hip_runtime.h>
#include <hip/hip_bf16.h>
#include <stdint.h>

// B=8192, D_IN=1024, D_HID=4096, D_OUT=1024, E=8
#define BB 8192
#define DIN 1024
#define DHID 4096
#define DOUT 1024
#define NEXP 8
#define GH_N 2048  // D_HID/2

typedef __attribute__((ext_vector_type(8))) __bf16 bf16x8;
typedef __attribute__((ext_vector_type(4))) float f32x4;

__device__ inline unsigned short f2bf(float f) {
  unsigned u = __builtin_bit_cast(unsigned, f);
  u = (u + 0x7FFFu + ((u >> 16) & 1u)) >> 16;
  return (unsigned short)u;
}
__device__ inline float b2f(unsigned short s) {
  return __builtin_bit_cast(float, (unsigned)s << 16);
}

// ---------------- elementwise f32 -> bf16 ----------------
__global__ void cvt_f32_bf16(const float* __restrict__ in,
                             unsigned short* __restrict__ out, int n4) {
  int i = blockIdx.x * blockDim.x + threadIdx.x;
  if (i >= n4) return;
  float4 v = ((const float4*)in)[i];
  ushort4 o;
  o.x = f2bf(v.x); o.y = f2bf(v.y); o.z = f2bf(v.z); o.w = f2bf(v.w);
  ((ushort4*)out)[i] = o;
}

// ---------------- transpose + convert: in[R][C] f32 -> out[C][R] bf16 ----------------
__global__ void transpose_cvt(const float* __restrict__ in,
                              unsigned short* __restrict__ out, int R, int C) {
  __shared__ float tile[32][33];
  int c0 = blockIdx.x * 32, r0 = blockIdx.y * 32;
  int tx = threadIdx.x & 31, ty = threadIdx.x >> 5;
#pragma unroll
  for (int i = 0; i < 4; ++i)
    tile[ty + i * 8][tx] = in[(size_t)(r0 + ty + i * 8) * C + c0 + tx];
  __syncthreads();
#pragma unroll
  for (int i = 0; i < 4; ++i)
    out[(size_t)(c0 + ty + i * 8) * R + r0 + tx] = f2bf(tile[tx][ty + i * 8]);
}

// ---------------- async global->LDS 16B ----------------
__device__ inline void gload16(const void* g, void* l) {
  __builtin_amdgcn_global_load_lds(
      (const __attribute__((address_space(1))) void*)g,
      (__attribute__((address_space(3))) void*)l, 16, 0, 0);
}

template <int N>
__device__ inline void waitv() {
  if constexpr (N == 0) asm volatile("s_waitcnt vmcnt(0)" ::: "memory");
  else if constexpr (N == 1) asm volatile("s_waitcnt vmcnt(1)" ::: "memory");
  else if constexpr (N == 2) asm volatile("s_waitcnt vmcnt(2)" ::: "memory");
  else if constexpr (N == 3) asm volatile("s_waitcnt vmcnt(3)" ::: "memory");
  else if constexpr (N == 4) asm volatile("s_waitcnt vmcnt(4)" ::: "memory");
  else asm volatile("s_waitcnt vmcnt(0)" ::: "memory");
}
__device__ inline void waitlgkm0() {
  asm volatile("s_waitcnt lgkmcnt(0)" ::: "memory");
  __builtin_amdgcn_sched_barrier(0);
}
__device__ inline bf16x8 ldr(const char* p) { return *(const bf16x8*)p; }

// ---------------- 4-phase quadrant GEMM (m201-style): C = A[M,K]*Bt[N,K]^T ----
// BN=256 fixed. 8 waves (2M x 4N), BK=64, 2 LDS buffers.
// Per K-tile: 4 phases = (r-half, c-half) quadrants, 16 (BM=256) or 8 (BM=128)
// MFMA each. A frags cached across ph0-1 / ph2-3, B(ch0) cached ph0->ph3.
// Stage units (8KB, 1 gload16/thread): B: 4 units/tile, A: BM/64 units/tile.
// LDS phys layouts put "needed-at-ph0" rows first:
//   A: [rh0/wm0][rh0/wm1][rh1/wm0][rh1/wm1]   B: [ch0 wn0..1][ch0 wn2..3][ch1 ...]
// Issue order per tile T (staging T+1 into buf^1): ph0: B0,B1; ph1: A-rh0;
// ph2: B2,B3; ph3: A-rh1.  Counted waits (steady state, per-wave):
//   end ph0: vmcnt(WS) retires B2,B3 (needed ph1); end ph1: vmcnt(WS) retires
//   A-rh1 units (needed ph2); end ph3: vmcnt(WS) retires next tile's ph0 set.
// Never vmcnt(0) except the last tile's drain.
template <int BM, int EPI>
__global__ __launch_bounds__(512, 2)
void gemmP(const unsigned short* __restrict__ A,
           const unsigned short* __restrict__ Bt,
           int M, int N, int K,
           const float* __restrict__ bias,
           unsigned short* __restrict__ outb,
           float* __restrict__ outf,
           const float* __restrict__ gates,
           int eidx, int accum) {
  constexpr int BN = 256;
  constexpr int WROWS = BM / 2;      // wave rows: 128 or 64
  constexpr int RM = WROWS / 16;     // row frags/wave: 8 or 4
  constexpr int HM = RM / 2;         // frags per r-half: 4 or 2
  constexpr int ABYTES = BM * 128;   // per-buffer A bytes (BK=64, 2B)
  constexpr int BBYTES = BN * 128;   // 32768
  constexpr int AUN = BM / 64;       // A stage units: 4 or 2
  constexpr int WS = (BM == 256) ? 4 : 3;   // steady-state wait count
  constexpr int W0L = (BM == 256) ? 2 : 1;  // ph0 wait on last tile

  __shared__ char lds[2 * (ABYTES + BBYTES)];
  char* Als = lds;
  char* Bls = lds + 2 * ABYTES;

  const int t = threadIdx.x;
  const int lane = t & 63;
  const int wid = t >> 6;
  const int wm = wid >> 2;
  const int wn = wid & 3;
  const int l15 = lane & 15, lg = lane >> 4;

  // bijective XCD swizzle (all grids %8==0)
  const int nwg = gridDim.x, flat = blockIdx.x;
  const int swz = (flat & 7) * (nwg >> 3) + (flat >> 3);
  const int nbn = N >> 8;
  const int bn = swz % nbn, bm = swz / nbn;
  const int m0 = bm * BM, n0 = bn * BN;

  // ---- stage source pointers (XOR chunk swizzle; involution shared w/ reads)
  const int prow = t >> 3;
  const int cOff = ((t & 7) ^ (prow & 7)) * 8;  // k-elem offset within tile
  const unsigned short* aP[AUN];
  const unsigned short* bP[4];
#pragma unroll
  for (int u = 0; u < AUN; ++u) {
    int p = u * 64 + prow;
    int g;
    if (BM == 256) g = ((p >> 6) & 1) * 128 + ((p >> 7) & 1) * 64 + (p & 63);
    else           g = ((p >> 5) & 1) * 64  + ((p >> 6) & 1) * 32 + (p & 31);
    aP[u] = A + (size_t)(m0 + g) * K + cOff;
  }
#pragma unroll
  for (int u = 0; u < 4; ++u) {
    int p = u * 64 + prow;
    int g = ((p >> 5) & 3) * 64 + ((p >> 7) & 1) * 32 + (p & 31);
    bP[u] = Bt + (size_t)(n0 + g) * K + cOff;
  }
  const int ldst = t * 16;

  // ---- LDS read bases ----
  const int slot0 = ((lg) ^ (l15 & 7)) * 16;       // ks=0
  const int slot1 = ((4 + lg) ^ (l15 & 7)) * 16;   // ks=1
  const int aRB0 = (0 * (BM / 2) + wm * (WROWS / 2) + l15) * 128;
  const int aRB1 = (1 * (BM / 2) + wm * (WROWS / 2) + l15) * 128;
  const int bCB0 = (0 * (BN / 2) + wn * 32 + l15) * 128;
  const int bCB1 = (1 * (BN / 2) + wn * 32 + l15) * 128;

  f32x4 acc[RM][4];
  const f32x4 zero = {0.f, 0.f, 0.f, 0.f};
#pragma unroll
  for (int i = 0; i < RM; ++i)
#pragma unroll
    for (int j = 0; j < 4; ++j) acc[i][j] = zero;

  bf16x8 ar[HM][2], bc0[2][2], bc1[2][2];

  const int NT = K >> 6;

  // ---- prologue: stage tile 0 in positional order, retire ph0-set ----
  {
    gload16(bP[0], Bls + 0 * 8192 + ldst);
    gload16(bP[1], Bls + 1 * 8192 + ldst);
    gload16(aP[0], Als + 0 * 8192 + ldst);
    if (AUN == 4) gload16(aP[1], Als + 1 * 8192 + ldst);
    gload16(bP[2], Bls + 2 * 8192 + ldst);
    gload16(bP[3], Bls + 3 * 8192 + ldst);
    if (AUN == 4) {
      gload16(aP[2], Als + 2 * 8192 + ldst);
      gload16(aP[3], Als + 3 * 8192 + ldst);
    } else {
      gload16(aP[1], Als + 1 * 8192 + ldst);
    }
  }
  waitv<WS>();
  __builtin_amdgcn_s_barrier();

  for (int T = 0; T < NT; ++T) {
    const int buf = T & 1;
    const char* Ab = Als + buf * ABYTES;
    const char* Bb = Bls + buf * BBYTES;
    char* An = Als + (buf ^ 1) * ABYTES;
    char* Bn = Bls + (buf ^ 1) * BBYTES;
    const bool stg = (T + 1 < NT);
    const int kn = (T + 1) << 6;

    // ======== ph0: read A rh0 + B ch0; stage B0,B1; mfma (rh0, cols 0-1)
#pragma unroll
    for (int f = 0; f < HM; ++f) {
      ar[f][0] = ldr(Ab + aRB0 + f * 2048 + slot0);
      ar[f][1] = ldr(Ab + aRB0 + f * 2048 + slot1);
    }
#pragma unroll
    for (int c = 0; c < 2; ++c) {
      bc0[c][0] = ldr(Bb + bCB0 + c * 2048 + slot0);
      bc0[c][1] = ldr(Bb + bCB0 + c * 2048 + slot1);
    }
    if (stg) {
      gload16(bP[0] + kn, Bn + 0 * 8192 + ldst);
      gload16(bP[1] + kn, Bn + 1 * 8192 + ldst);
    }
    __builtin_amdgcn_s_barrier();
    waitlgkm0();
    __builtin_amdgcn_s_setprio(1);
#pragma unroll
    for (int ks = 0; ks < 2; ++ks)
#pragma unroll
      for (int f = 0; f < HM; ++f)
#pragma unroll
        for (int c = 0; c < 2; ++c)
          acc[f][c] = __builtin_amdgcn_mfma_f32_16x16x32_bf16(
              ar[f][ks], bc0[c][ks], acc[f][c], 0, 0, 0);
    __builtin_amdgcn_s_setprio(0);
    if (stg) waitv<WS>(); else waitv<W0L>();
    __builtin_amdgcn_s_barrier();

    // ======== ph1: read B ch1; stage A-rh0 units; mfma (rh0, cols 2-3)
#pragma unroll
    for (int c = 0; c < 2; ++c) {
      bc1[c][0] = ldr(Bb + bCB1 + c * 2048 + slot0);
      bc1[c][1] = ldr(Bb + bCB1 + c * 2048 + slot1);
    }
    if (stg) {
      gload16(aP[0] + kn, An + 0 * 8192 + ldst);
      if (AUN == 4) gload16(aP[1] + kn, An + 1 * 8192 + ldst);
    }
    __builtin_amdgcn_s_barrier();
    waitlgkm0();
    __builtin_amdgcn_s_setprio(1);
#pragma unroll
    for (int ks = 0; ks < 2; ++ks)
#pragma unroll
      for (int f = 0; f < HM; ++f)
#pragma unroll
        for (int c = 0; c < 2; ++c)
          acc[f][2 + c] = __builtin_amdgcn_mfma_f32_16x16x32_bf16(
              ar[f][ks], bc1[c][ks], acc[f][2 + c], 0, 0, 0);
    __builtin_amdgcn_s_setprio(0);
    if (stg) waitv<WS>(); else waitv<0>();
    __builtin_amdgcn_s_barrier();

    // ======== ph2: read A rh1; stage B2,B3; mfma (rh1, cols 2-3)
#pragma unroll
    for (int f = 0; f < HM; ++f) {
      ar[f][0] = ldr(Ab + aRB1 + f * 2048 + slot0);
      ar[f][1] = ldr(Ab + aRB1 + f * 2048 + slot1);
    }
    if (stg) {
      gload16(bP[2] + kn, Bn + 2 * 8192 + ldst);
      gload16(bP[3] + kn, Bn + 3 * 8192 + ldst);
    }
    __builtin_amdgcn_s_barrier();
    waitlgkm0();
    __builtin_amdgcn_s_setprio(1);
#pragma unroll
    for (int ks = 0; ks < 2; ++ks)
#pragma unroll
      for (int f = 0; f < HM; ++f)
#pragma unroll
        for (int c = 0; c < 2; ++c)
          acc[HM + f][2 + c] = __builtin_amdgcn_mfma_f32_16x16x32_bf16(
              ar[f][ks], bc1[c][ks], acc[HM + f][2 + c], 0, 0, 0);
    __builtin_amdgcn_s_setprio(0);
    __builtin_amdgcn_s_barrier();  // no vmcnt here

    // ======== ph3: no ds_reads; stage A-rh1 units; mfma (rh1, cols 0-1)
    if (stg) {
      if (AUN == 4) {
        gload16(aP[2] + kn, An + 2 * 8192 + ldst);
        gload16(aP[3] + kn, An + 3 * 8192 + ldst);
      } else {
        gload16(aP[1] + kn, An + 1 * 8192 + ldst);
      }
    }
    __builtin_amdgcn_s_barrier();
    __builtin_amdgcn_s_setprio(1);
#pragma unroll
    for (int ks = 0; ks < 2; ++ks)
#pragma unroll
      for (int f = 0; f < HM; ++f)
#pragma unroll
        for (int c = 0; c < 2; ++c)
          acc[HM + f][c] = __builtin_amdgcn_mfma_f32_16x16x32_bf16(
              ar[f][ks], bc0[c][ks], acc[HM + f][c], 0, 0, 0);
    __builtin_amdgcn_s_setprio(0);
    if (stg) waitv<WS>();
    __builtin_amdgcn_s_barrier();
  }

  // ---- epilogue: D row = lg*4 + reg (within 16), col = l15 ----
  const int rb = m0 + wm * WROWS + (lg << 2);
  const int cb = n0 + wn * 64 + l15;
  if (EPI == 0) {
#pragma unroll
    for (int fg = 0; fg < RM; ++fg) {
#pragma unroll
      for (int j = 0; j < 4; ++j) {
        int col = cb + j * 16;
        float bv = bias[col];
#pragma unroll
        for (int r = 0; r < 4; ++r) {
          int row = rb + fg * 16 + r;
          float v = acc[fg][j][r] + bv;
          outb[(size_t)row * N + col] = f2bf(fmaxf(v, 0.f));
        }
      }
    }
  } else {
#pragma unroll
    for (int fg = 0; fg < RM; ++fg) {
      float g[4];
#pragma unroll
      for (int r = 0; r < 4; ++r)
        g[r] = gates[(size_t)(rb + fg * 16 + r) * NEXP + eidx];
#pragma unroll
      for (int j = 0; j < 4; ++j) {
        int col = cb + j * 16;
        float bv = bias[col];
#pragma unroll
        for (int r = 0; r < 4; ++r) {
          size_t o = (size_t)(rb + fg * 16 + r) * N + col;
          float v = (acc[fg][j][r] + bv) * g[r];
          outf[o] = accum ? outf[o] + v : v;
        }
      }
    }
  }
}

// ---------------- gating head v2: one wave per row, gW2^T in LDS ----------------
__global__ __launch_bounds__(512)
void gating_head2(const unsigned short* __restrict__ gh,
                  const float* __restrict__ gW2,
                  const float* __restrict__ gb2,
                  float* __restrict__ gws,
                  float* __restrict__ g1,
                  float* __restrict__ g2) {
  __shared__ float wT[8][2048];  // 64 KB, e-major -> conflict-free float4 reads
  const int t = threadIdx.x;
  for (int idx = t; idx < 16384; idx += 512) {
    wT[idx & 7][idx >> 3] = gW2[idx];
  }
  __syncthreads();
  const int wid = t >> 6, lane = t & 63;
  const int row = blockIdx.x * 8 + wid;
  const unsigned short* ghr = gh + (size_t)row * 2048;
  float s[8] = {0.f, 0.f, 0.f, 0.f, 0.f, 0.f, 0.f, 0.f};
#pragma unroll
  for (int j = 0; j < 8; ++j) {
    int k4 = lane + 64 * j;  // covers k = 4*k4 .. 4*k4+3
    ushort4 hv = ((const ushort4*)ghr)[k4];
    float h0 = b2f(hv.x), h1 = b2f(hv.y), h2 = b2f(hv.z), h3 = b2f(hv.w);
#pragma unroll
    for (int e = 0; e < 8; ++e) {
      float4 w = ((const float4*)&wT[e][0])[k4];
      s[e] += h0 * w.x + h1 * w.y + h2 * w.z + h3 * w.w;
    }
  }
#pragma unroll
  for (int e = 0; e < 8; ++e)
#pragma unroll
    for (int off = 1; off < 64; off <<= 1) s[e] += __shfl_xor(s[e], off, 64);
  if (lane == 0) {
    float l[8], m = -1e30f;
#pragma unroll
    for (int e = 0; e < 8; ++e) {
      l[e] = s[e] + gb2[e];
      m = fmaxf(m, l[e]);
    }
    float sum = 0.f;
#pragma unroll
    for (int e = 0; e < 8; ++e) {
      l[e] = expf(l[e] - m);
      sum += l[e];
    }
    float inv = 1.f / sum;
#pragma unroll
    for (int e = 0; e < 8; ++e) {
      float gv = l[e] * inv;
      gws[(size_t)row * 8 + e] = gv;
      g1[(size_t)row * 8 + e] = gv;
      g2[(size_t)row * 8 + e] = gv;
    }
  }
}

extern "C" void kernel_launch(void* const* d_in, const int* in_sizes, int n_in,
                              void* d_out, int out_size, void* d_ws,
                              size_t ws_size, hipStream_t stream) {
  (void)in_sizes; (void)n_in; (void)out_size; (void)ws_size;
  const float* x   = (const float*)d_in[0];
  const float* gW1 = (const float*)d_in[1];
  const float* gb1 = (const float*)d_in[2];
  const float* gW2 = (const float*)d_in[3];
  const float* gb2 = (const float*)d_in[4];
  const float* eW1 = (const float*)d_in[5];
  const float* eb1 = (const float*)d_in[6];
  const float* eW2 = (const float*)d_in[7];
  const float* eb2 = (const float*)d_in[8];

  float* outC  = (float*)d_out;                       // [8192,1024]
  float* outG1 = outC + (size_t)BB * DOUT;            // [8192,8]
  float* outG2 = outG1 + (size_t)BB * NEXP;           // [8192,8]

  char* ws = (char*)d_ws;
  unsigned short* xb   = (unsigned short*)(ws);                 // 16,777,216 B
  unsigned short* gW1T = (unsigned short*)(ws + 16777216);      //  4,194,304 B
  unsigned short* gh   = (unsigned short*)(ws + 20971520);      // 33,554,432 B
  float*          gat  = (float*)(ws + 54525952);               //    262,144 B
  unsigned short* w1T  = (unsigned short*)(ws + 54788096);      //  8,388,608 B
  unsigned short* w2T  = (unsigned short*)(ws + 63176704);      //  8,388,608 B
  unsigned short* hbuf = (unsigned short*)(ws + 71565312);      // 67,108,864 B

  // x -> bf16
  cvt_f32_bf16<<<(BB * DIN / 4) / 256, 256, 0, stream>>>(x, xb, BB * DIN / 4);
  // gW1 [1024][2048] -> gW1T [2048][1024] bf16
  transpose_cvt<<<dim3(GH_N / 32, DIN / 32), 256, 0, stream>>>(gW1, gW1T, DIN, GH_N);
  // gh = relu(x @ gW1 + gb1)  [8192, 2048]   grid 32*8=256
  gemmP<256, 0><<<dim3((BB / 256) * (GH_N / 256)), 512, 0, stream>>>(
      xb, gW1T, BB, GH_N, DIN, gb1, gh, nullptr, nullptr, 0, 0);
  // gates = softmax(gh @ gW2 + gb2)  (1024 blocks x 8 rows)
  gating_head2<<<BB / 8, 512, 0, stream>>>(gh, gW2, gb2, gat, outG1, outG2);

  for (int e = 0; e < NEXP; ++e) {
    transpose_cvt<<<dim3(DHID / 32, DIN / 32), 256, 0, stream>>>(
        eW1 + (size_t)e * DIN * DHID, w1T, DIN, DHID);
    transpose_cvt<<<dim3(DOUT / 32, DHID / 32), 256, 0, stream>>>(
        eW2 + (size_t)e * DHID * DOUT, w2T, DHID, DOUT);
    // h = relu(x @ eW1_e + eb1_e)  [8192, 4096]   grid 32*16=512
    gemmP<256, 0><<<dim3((BB / 256) * (DHID / 256)), 512, 0, stream>>>(
        xb, w1T, BB, DHID, DIN, eb1 + (size_t)e * DHID, hbuf, nullptr, nullptr, 0, 0);
    // combined (+)= gates[:,e] * (h @ eW2_e + eb2_e)   grid 64*4=256 (full chip)
    gemmP<128, 1><<<dim3((BB / 128) * (DOUT / 256)), 512, 0, stream>>>(
        hbuf, w2T, BB, DOUT, DHID, eb2 + (size_t)e * DOUT, nullptr, outC, gat, e, e > 0);
  }
}